// Round 1
// baseline (670.057 us; speedup 1.0000x reference)
//
#include <hip/hip_runtime.h>

#define N_PTS 524288
#define DIM   64
#define K_CL  512

// ---------------------------------------------------------------------------
// Pre-kernel: half squared norms of centers -> ws
// ---------------------------------------------------------------------------
__global__ void c2_kernel(const float* __restrict__ centers,
                          float* __restrict__ halfc2) {
    int k = blockIdx.x * blockDim.x + threadIdx.x;
    if (k < K_CL) {
        const float4* c4 = (const float4*)(centers + k * DIM);
        float s = 0.f;
#pragma unroll
        for (int i = 0; i < DIM / 4; ++i) {
            float4 v = c4[i];
            s += v.x * v.x + v.y * v.y + v.z * v.z + v.w * v.w;
        }
        halfc2[k] = 0.5f * s;
    }
}

// ---------------------------------------------------------------------------
// Fused assign + per-block partial segment-sum.
// 256 blocks (one per CU) x 1024 threads. Each thread handles 2 points.
// Centers are read via block-uniform addresses -> scalar loads (SGPR
// broadcast into v_fmac), so LDS is free for the partial sums.
// LDS partial sums padded to stride 65 floats: bank = (65*k + d) % 32
// = (k + d) % 32 -> spread across banks by cluster index.
// ---------------------------------------------------------------------------
__global__ __launch_bounds__(1024)
void assign_reduce_kernel(const float* __restrict__ x,
                          const float* __restrict__ centers,
                          const float* __restrict__ halfc2,
                          float* __restrict__ gsums,   // [K_CL*DIM]
                          float* __restrict__ gcnt) {  // [K_CL]
    __shared__ float lds_sums[K_CL * 65];
    __shared__ float lds_cnt[K_CL];

    for (int i = threadIdx.x; i < K_CL * 65; i += 1024) lds_sums[i] = 0.f;
    if (threadIdx.x < K_CL) lds_cnt[threadIdx.x] = 0.f;
    __syncthreads();

    const int pt_base = blockIdx.x * 2048 + threadIdx.x;

    for (int it = 0; it < 2; ++it) {
        const int p = pt_base + it * 1024;
        const float4* xp = (const float4*)(x + (size_t)p * DIM);
        float4 xr[16];
#pragma unroll
        for (int i = 0; i < 16; ++i) xr[i] = xp[i];

        float best = 3.4e38f;
        int   bidx = 0;

#pragma unroll 2
        for (int k = 0; k < K_CL; ++k) {
            const float4* cp = (const float4*)(centers + k * DIM);
            float a0 = 0.f, a1 = 0.f, a2 = 0.f, a3 = 0.f;
#pragma unroll
            for (int i = 0; i < 16; ++i) {
                float4 c = cp[i];   // uniform address -> s_load, SGPR operand
                a0 = fmaf(xr[i].x, c.x, a0);
                a1 = fmaf(xr[i].y, c.y, a1);
                a2 = fmaf(xr[i].z, c.z, a2);
                a3 = fmaf(xr[i].w, c.w, a3);
            }
            float score = halfc2[k] - ((a0 + a1) + (a2 + a3));
            if (score < best) { best = score; bidx = k; }
        }

        // accumulate this point into the block-local partial sums
        float* dst = &lds_sums[bidx * 65];
#pragma unroll
        for (int i = 0; i < 16; ++i) {
            atomicAdd(&dst[4 * i + 0], xr[i].x);
            atomicAdd(&dst[4 * i + 1], xr[i].y);
            atomicAdd(&dst[4 * i + 2], xr[i].z);
            atomicAdd(&dst[4 * i + 3], xr[i].w);
        }
        atomicAdd(&lds_cnt[bidx], 1.0f);
    }
    __syncthreads();

    // flush block partials to global accumulators
    for (int i = threadIdx.x; i < K_CL * DIM; i += 1024) {
        int k = i >> 6, d = i & 63;
        atomicAdd(&gsums[i], lds_sums[k * 65 + d]);
    }
    if (threadIdx.x < K_CL) atomicAdd(&gcnt[threadIdx.x], lds_cnt[threadIdx.x]);
}

// ---------------------------------------------------------------------------
// Finalize: means (or keep old center when count==0) + counts -> d_out
// d_out layout: new_centers [512*64] then counts [512]
// ---------------------------------------------------------------------------
__global__ void finalize_kernel(const float* __restrict__ gsums,
                                const float* __restrict__ gcnt,
                                const float* __restrict__ centers,
                                float* __restrict__ out) {
    int i = blockIdx.x * 256 + threadIdx.x;
    if (i < K_CL * DIM) {
        int k = i >> 6;
        float c = gcnt[k];
        out[i] = (c > 0.f) ? (gsums[i] / c) : centers[i];
    } else if (i < K_CL * DIM + K_CL) {
        out[i] = gcnt[i - K_CL * DIM];
    }
}

extern "C" void kernel_launch(void* const* d_in, const int* in_sizes, int n_in,
                              void* d_out, int out_size, void* d_ws, size_t ws_size,
                              hipStream_t stream) {
    const float* x       = (const float*)d_in[0];
    const float* centers = (const float*)d_in[1];

    float* ws     = (float*)d_ws;
    float* gsums  = ws;                 // 32768 floats
    float* gcnt   = ws + K_CL * DIM;    // 512 floats
    float* hc2    = ws + K_CL * DIM + K_CL; // 512 floats

    hipMemsetAsync(ws, 0, (K_CL * DIM + K_CL) * sizeof(float), stream);
    c2_kernel<<<2, 256, 0, stream>>>(centers, hc2);
    assign_reduce_kernel<<<256, 1024, 0, stream>>>(x, centers, hc2, gsums, gcnt);
    finalize_kernel<<<(K_CL * DIM + K_CL + 255) / 256, 256, 0, stream>>>(
        gsums, gcnt, centers, (float*)d_out);
}